// Round 12
// baseline (1430.446 us; speedup 1.0000x reference)
//
#include <hip/hip_runtime.h>

// Problem constants (match reference)
#define SEQ 2048
#define BAT 256
#define KD  64
#define HD  128
#define SBH (SEQ * BAT * HD)

typedef _Float16 half2v  __attribute__((ext_vector_type(2)));  // fdot2 operand type
typedef __fp16   fp16x2  __attribute__((ext_vector_type(2)));  // cvt_pkrtz return type

// DPP helpers. CTRL: 0xB1 = quad_perm(1,0,3,2) = lane^1; 0x4E = quad_perm(2,3,0,1)
// = lane^2; 0x128 = row_ror:8 = lane^8 within 16-lane row; 0x124/0x12C =
// row_ror:4 / row_ror:12 (together + select = lane^4 exchange).
template<int CTRL>
__device__ __forceinline__ float dpp_add(float keep, float send) {
    const int r = __builtin_amdgcn_update_dpp(0, __float_as_int(send),
                                              CTRL, 0xF, 0xF, true);
    return keep + __int_as_float(r);
}
template<int CTRL>
__device__ __forceinline__ float dpp_mov(float send) {
    const int r = __builtin_amdgcn_update_dpp(0, __float_as_int(send),
                                              CTRL, 0xF, 0xF, true);
    return __int_as_float(r);
}

// Pack two f32 -> f16x2 bits (v_cvt_pkrtz_f16_f32).
__device__ __forceinline__ int PK(float a, float b) {
    fp16x2 p = __builtin_amdgcn_cvt_pkrtz(a, b);
    return __builtin_bit_cast(int, p);
}

// f32 += dot2(f16x2, f16x2) — v_dot2_f32_f16 (r11 A/B: 32 fdot2 beats 64 fma).
__device__ __forceinline__ float fdot2(int w, int h, float c) {
#if __has_builtin(__builtin_amdgcn_fdot2)
    return __builtin_amdgcn_fdot2(__builtin_bit_cast(half2v, w),
                                  __builtin_bit_cast(half2v, h), c, false);
#else
    half2v wv = __builtin_bit_cast(half2v, w), hv = __builtin_bit_cast(half2v, h);
    return fmaf((float)wv[1], (float)hv[1], fmaf((float)wv[0], (float)hv[0], c));
#endif
}

// Pin a scalar into a register (loads can't sink past the volatile asm).
#define PIN(x) asm volatile("" : "+v"(x))

// LDS-visibility-only barrier: does NOT drain vmcnt (output stores stay in
// flight; they need no ordering with the barrier).
#define STEP_BARRIER() do {                                   \
    asm volatile("s_waitcnt lgkmcnt(0)" ::: "memory");        \
    __builtin_amdgcn_s_barrier();                             \
    asm volatile("" ::: "memory");                            \
} while (0)

// ---------------------------------------------------------------------------
// Kernel 1: precompute type-dependent tables into d_ws (f32).
//   tabH[ty][r] = sum_k embed_W[ty][k]*W_ih[r][k] + b_ih[r] + b_hh[r]
//   tabD[ty][r] = sum_k embed_W[ty][k]*dec_W[r][k] + dec_b[r]
// ---------------------------------------------------------------------------
__global__ __launch_bounds__(128) void precompute_tables(
    const float* __restrict__ embed_W, const float* __restrict__ W_ih,
    const float* __restrict__ b_ih,    const float* __restrict__ b_hh,
    const float* __restrict__ dec_W,   const float* __restrict__ dec_b,
    float* __restrict__ tabH, float* __restrict__ tabD)
{
    __shared__ float x[KD];
    const int ty = blockIdx.x;   // 0..64 (row 64 = padding, embed row is zero)
    const int r  = threadIdx.x;  // 0..127
    if (r < KD) x[r] = embed_W[ty * KD + r];
    __syncthreads();
    float ah = 0.f, ad = 0.f;
#pragma unroll
    for (int k = 0; k < KD; ++k) {
        const float xv = x[k];
        ah += xv * W_ih[r * KD + k];
        ad += xv * dec_W[r * (KD + HD) + k];
    }
    tabH[ty * HD + r] = ah + b_ih[r] + b_hh[r];
    tabD[ty * HD + r] = ad + dec_b[r];
}

// ---------------------------------------------------------------------------
// Kernel 2: persistent per-batch-element recurrence. One WG per batch elem,
// 1024 threads = 16 waves (doubles waves/SIMD 2 -> 4 vs round 8: the step is
// latency-bound on the ds_read -> dot -> DPP/trans -> barrier chain and 256
// single-block CUs can't add blocks, so add waves).
// Lane bits (lane = tid&63):
//   b0: row LSB (value-halving) AND chunk bit0
//   b1: chunk bit1 (plain-add stage)     b3: chunk bit2 (plain-add stage)
//   b2: type (0=hidden/W_hh, 1=decay/dec_W)
//   bits4-5 + wave: row pair P = wave*4 + (lane>>4), rows 2P / 2P+1
// chunk = b0|b1<<1|b3<<2 (8 chunks x 16 h-cols). Each lane: 2 rows x 16 cols,
// 16 f16x2 weight dwords (pinned), 16 fdot2/step.
// Reduction: xor1 value-halving (resolve row LSB), xor2 + xor8 plain DPP adds.
// Type exchange lane^4 via row_ror:4/12 + select. Output tasks on b1==0 lanes:
// (b2,b3)=(0,0) store hidden, (0,1) store hidden_ti, (1,0) store decay,
// (1,1) LDS-write h_new. h double-buffered LDS f16; one lgkm-only barrier.
// ---------------------------------------------------------------------------
__global__ __launch_bounds__(1024, 4) void hawkes_rnn(
    const float* __restrict__ dt_g,  const float* __restrict__ h0,
    const float* __restrict__ W_hh,  const float* __restrict__ dec_W,
    const int*   __restrict__ seq_types,
    const float* __restrict__ tabH,  const float* __restrict__ tabD,
    float* __restrict__ out)
{
    __shared__ float dts[SEQ];                        // 8,192 B
    __shared__ int   tys[SEQ + 2];                    // 8,200 B
    __shared__ __align__(16) _Float16 h16[2][HD];     //   512 B

    const int b    = blockIdx.x;
    const int tid  = threadIdx.x;
    const int lane = tid & 63;
    const int b0 = lane & 1, b1 = (lane >> 1) & 1;
    const int b2 = (lane >> 2) & 1, b3 = (lane >> 3) & 1;
    const int P    = (tid >> 6) * 4 + (lane >> 4);        // row pair 0..63
    const int row  = 2 * P + b0;                          // row this lane finalizes
    const int chunk = b0 | (b1 << 1) | (b3 << 2);         // h-col block /16
    const bool clsH = (b2 & b3) && !b1;                   // LDS h-writer lane

    // Stage dt / seq_types columns for this batch element.
    for (int t = tid; t < SEQ; t += 1024) {
        dts[t] = dt_g[(size_t)t * BAT + b];
        tys[t] = seq_types[(size_t)t * BAT + b];
    }
    if (tid < 2) tys[SEQ + tid] = 0;          // prefetch-pad
    if (tid < HD) h16[0][tid] = (_Float16)h0[b * HD + tid];

    // Load this lane's weight block (rows 2P, 2P+1 x cols chunk*16..+15,
    // f32 -> f16x2) into named pinned registers: 16 dwords.
    const size_t rstr = b2 ? (size_t)(KD + HD) : (size_t)HD;
    const float* wbase = (b2 ? (dec_W + KD) : W_hh) + (size_t)(2 * P) * rstr
                         + chunk * 16;
    int wa0,wa1,wa2,wa3,wa4,wa5,wa6,wa7;   // row 2P
    int wb0,wb1,wb2,wb3,wb4,wb5,wb6,wb7;   // row 2P+1
    {
        const float4 a0 = *reinterpret_cast<const float4*>(wbase + 0);
        const float4 a1 = *reinterpret_cast<const float4*>(wbase + 4);
        const float4 a2 = *reinterpret_cast<const float4*>(wbase + 8);
        const float4 a3 = *reinterpret_cast<const float4*>(wbase + 12);
        wa0 = PK(a0.x,a0.y); wa1 = PK(a0.z,a0.w); wa2 = PK(a1.x,a1.y); wa3 = PK(a1.z,a1.w);
        wa4 = PK(a2.x,a2.y); wa5 = PK(a2.z,a2.w); wa6 = PK(a3.x,a3.y); wa7 = PK(a3.z,a3.w);
        const float4 c0 = *reinterpret_cast<const float4*>(wbase + rstr + 0);
        const float4 c1 = *reinterpret_cast<const float4*>(wbase + rstr + 4);
        const float4 c2 = *reinterpret_cast<const float4*>(wbase + rstr + 8);
        const float4 c3 = *reinterpret_cast<const float4*>(wbase + rstr + 12);
        wb0 = PK(c0.x,c0.y); wb1 = PK(c0.z,c0.w); wb2 = PK(c1.x,c1.y); wb3 = PK(c1.z,c1.w);
        wb4 = PK(c2.x,c2.y); wb5 = PK(c2.z,c2.w); wb6 = PK(c3.x,c3.y); wb7 = PK(c3.z,c3.w);
    }
    PIN(wa0);PIN(wa1);PIN(wa2);PIN(wa3);PIN(wa4);PIN(wa5);PIN(wa6);PIN(wa7);
    PIN(wb0);PIN(wb1);PIN(wb2);PIN(wb3);PIN(wb4);PIN(wb5);PIN(wb6);PIN(wb7);

    const float* tabp = (b2 ? tabD : tabH) + row;

    // Per-lane 32-bit element offset for the single global store this lane
    // owns (advanced by BAT*HD per step). clsH / b1==1 lanes never store.
    unsigned off = (unsigned)(b2 ? (unsigned)SBH
                                 : (b3 ? 2u * SBH : 0u))
                   + (unsigned)(b * HD + row);

    __syncthreads();   // staging (dt/ty/h0) visible

    // Table prefetch pipeline (2 steps ahead; tables are L2-resident).
    float tab_cur = tabp[tys[0] * HD];
    float tab_nxt = tabp[tys[1] * HD];

#define DOT8(A,W0,W1,W2,W3,W4,W5,W6,W7) \
    A = fdot2(W0, hv0.x, A); A = fdot2(W1, hv0.y, A); \
    A = fdot2(W2, hv0.z, A); A = fdot2(W3, hv0.w, A); \
    A = fdot2(W4, hv1.x, A); A = fdot2(W5, hv1.y, A); \
    A = fdot2(W6, hv1.z, A); A = fdot2(W7, hv1.w, A);

#define STEP(P_, TT) { \
    const float tab_pf = tabp[tys[(TT) + 2] * HD];   /* use at TT+2 */ \
    const float dtv    = dts[TT]; \
    /* h chunk: 2 broadcast ds_read_b128 (16 f16; 32B stride = free 2-way) */ \
    const int4 hv0 = *reinterpret_cast<const int4*>(&h16[P_][chunk * 16]); \
    const int4 hv1 = *reinterpret_cast<const int4*>(&h16[P_][chunk * 16 + 8]); \
    float a0 = 0.f, a1 = 0.f; \
    DOT8(a0, wa0,wa1,wa2,wa3,wa4,wa5,wa6,wa7) \
    DOT8(a1, wb0,wb1,wb2,wb3,wb4,wb5,wb6,wb7) \
    /* stage 1 (xor1, value-halving): resolve row LSB */ \
    const float t0 = dpp_add<0xB1>(b0 ? a1 : a0, b0 ? a0 : a1); \
    /* stages 2,3 (xor2, xor8): plain adds over chunk bits */ \
    const float u  = dpp_add<0x4E>(t0, t0); \
    const float sv = dpp_add<0x128>(u, u) + tab_cur; \
    /* activations (branchless; all lanes both paths) */ \
    const float e2 = __expf(2.f * sv); \
    const float vh = 1.f - __fdividef(2.f, e2 + 1.f);            /* tanh */ \
    const float z  = 10.f * sv; \
    const float em = __expf(-fabsf(z)); \
    const float sp = 0.1f * (fmaxf(z, 0.f) + __logf(1.f + em));  /* softplus10 */ \
    const float vd = __expf(-sp * dtv); \
    const float v  = b2 ? vd : vh; \
    /* type exchange lane^4: row_ror:4 / row_ror:12 + select */ \
    const float x4  = dpp_mov<0x124>(v); \
    const float x12 = dpp_mov<0x12C>(v); \
    const float cross = b2 ? x12 : x4; \
    const float hnew  = v * cross; \
    if (clsH) { \
        h16[(P_) ^ 1][row] = (_Float16)hnew; \
    } else if (!b1 && !(b2 & b3)) { \
        const float stv = b2 ? sp : (b3 ? hnew : v); \
        out[off] = stv; \
    } \
    off += BAT * HD; \
    tab_cur = tab_nxt; \
    tab_nxt = tab_pf; \
    STEP_BARRIER(); \
}

    for (int t = 0; t < SEQ; t += 2) {
        STEP(0, t)
        STEP(1, t + 1)
    }
#undef STEP
#undef DOT8
}

extern "C" void kernel_launch(void* const* d_in, const int* in_sizes, int n_in,
                              void* d_out, int out_size, void* d_ws, size_t ws_size,
                              hipStream_t stream) {
    const float* dt        = (const float*)d_in[0];
    const float* h0        = (const float*)d_in[1];
    const float* embed_W   = (const float*)d_in[2];
    const float* W_ih      = (const float*)d_in[3];
    const float* b_ih      = (const float*)d_in[4];
    const float* W_hh      = (const float*)d_in[5];
    const float* b_hh      = (const float*)d_in[6];
    const float* dec_W     = (const float*)d_in[7];
    const float* dec_b     = (const float*)d_in[8];
    const int*   seq_types = (const int*)  d_in[9];
    float* out  = (float*)d_out;

    float* tabHw = (float*)d_ws;                 // [65][128]
    float* tabDw = tabHw + (KD + 1) * HD;        // [65][128]

    precompute_tables<<<KD + 1, 128, 0, stream>>>(embed_W, W_ih, b_ih, b_hh,
                                                  dec_W, dec_b, tabHw, tabDw);
    hawkes_rnn<<<BAT, 1024, 0, stream>>>(dt, h0, W_hh, dec_W, seq_types,
                                         tabHw, tabDw, out);
}

// Round 13
// 1014.662 us; speedup vs baseline: 1.4098x; 1.4098x over previous
//
#include <hip/hip_runtime.h>

// Problem constants (match reference)
#define SEQ 2048
#define BAT 256
#define KD  64
#define HD  128

typedef _Float16 half2v  __attribute__((ext_vector_type(2)));  // fdot2 operand type
typedef __fp16   fp16x2  __attribute__((ext_vector_type(2)));  // cvt_pkrtz return type

// DPP helpers. CTRL: 0xB1 = quad_perm(1,0,3,2) = lane^1; 0x4E = quad_perm(2,3,0,1)
// = lane^2; 0x128 = row_ror:8 = lane^8 within 16-lane row; 0x124/0x12C =
// row_ror:4 / row_ror:12 (together + select = lane^4 exchange).
template<int CTRL>
__device__ __forceinline__ float dpp_add(float keep, float send) {
    const int r = __builtin_amdgcn_update_dpp(0, __float_as_int(send),
                                              CTRL, 0xF, 0xF, true);
    return keep + __int_as_float(r);
}
template<int CTRL>
__device__ __forceinline__ float dpp_mov(float send) {
    const int r = __builtin_amdgcn_update_dpp(0, __float_as_int(send),
                                              CTRL, 0xF, 0xF, true);
    return __int_as_float(r);
}

// Pack two f32 -> f16x2 bits (v_cvt_pkrtz_f16_f32).
__device__ __forceinline__ int PK(float a, float b) {
    fp16x2 p = __builtin_amdgcn_cvt_pkrtz(a, b);
    return __builtin_bit_cast(int, p);
}

// f32 += dot2(f16x2, f16x2) — v_dot2_f32_f16 (2 MACs / inst), f32 accumulate.
__device__ __forceinline__ float fdot2(int w, int h, float c) {
#if __has_builtin(__builtin_amdgcn_fdot2)
    return __builtin_amdgcn_fdot2(__builtin_bit_cast(half2v, w),
                                  __builtin_bit_cast(half2v, h), c, false);
#else
    half2v wv = __builtin_bit_cast(half2v, w), hv = __builtin_bit_cast(half2v, h);
    return fmaf((float)wv[1], (float)hv[1], fmaf((float)wv[0], (float)hv[0], c));
#endif
}

// Pin a scalar into a register (loads can't sink past the volatile asm).
#define PIN(x) asm volatile("" : "+v"(x))

// LDS-visibility-only barrier: does NOT drain vmcnt (output stores stay in
// flight; they need no ordering with the barrier).
#define STEP_BARRIER() do {                                   \
    asm volatile("s_waitcnt lgkmcnt(0)" ::: "memory");        \
    __builtin_amdgcn_s_barrier();                             \
    asm volatile("" ::: "memory");                            \
} while (0)

// ---------------------------------------------------------------------------
// Kernel 1: precompute type-dependent tables into d_ws (f32).
//   tabH[ty][r] = sum_k embed_W[ty][k]*W_ih[r][k] + b_ih[r] + b_hh[r]
//   tabD[ty][r] = sum_k embed_W[ty][k]*dec_W[r][k] + dec_b[r]
// ---------------------------------------------------------------------------
__global__ __launch_bounds__(128) void precompute_tables(
    const float* __restrict__ embed_W, const float* __restrict__ W_ih,
    const float* __restrict__ b_ih,    const float* __restrict__ b_hh,
    const float* __restrict__ dec_W,   const float* __restrict__ dec_b,
    float* __restrict__ tabH, float* __restrict__ tabD)
{
    __shared__ float x[KD];
    const int ty = blockIdx.x;   // 0..64 (row 64 = padding, embed row is zero)
    const int r  = threadIdx.x;  // 0..127
    if (r < KD) x[r] = embed_W[ty * KD + r];
    __syncthreads();
    float ah = 0.f, ad = 0.f;
#pragma unroll
    for (int k = 0; k < KD; ++k) {
        const float xv = x[k];
        ah += xv * W_ih[r * KD + k];
        ad += xv * dec_W[r * (KD + HD) + k];
    }
    tabH[ty * HD + r] = ah + b_ih[r] + b_hh[r];
    tabD[ty * HD + r] = ad + dec_b[r];
}

// ---------------------------------------------------------------------------
// Kernel 2: persistent per-batch-element recurrence. One WG per batch elem,
// 512 threads = 8 waves. IDENTICAL to the round-8 kernel (best, 1007 us)
// EXCEPT __launch_bounds__(512, 1): the min-waves=2 target made the register
// allocator shrink arch-VGPR pressure by parking the 32 pinned weight dwords
// in AGPRs, paying an accvgpr-read-class copy on every use in the loop
// (observed ~206 issued insts/wave/step vs ~90 in source; VGPR_Count=40).
// min-waves=1 relaxes the budget; block=512 still caps VGPRs at 256, so the
// real 2-waves/SIMD occupancy is unchanged.
// Lane bits (lane = tid&63): b0,b1 = row-low bits AND chunk bits (value-
// halving); b2 = type (0=hidden,1=decay); b3 = chunk bit 2 / duplicate tag;
// bits4-5 + wave: row quad G. chunk = b0|b1<<1|b3<<2; row = 4G + 2*b0 + b1.
// Reduction all-DPP: xor1/xor2 value-halving, xor8 plain add. Type exchange
// lane^4 via row_ror:4/12 + select. Each lane does EXACTLY ONE output task:
// (b2,b3)=(0,0) store hidden, (0,1) store hidden_ti, (1,0) store decay,
// (1,1) LDS-write h_new. h double-buffered LDS f16; one lgkm-only barrier.
// ---------------------------------------------------------------------------
__global__ __launch_bounds__(512, 1) void hawkes_rnn(
    const float* __restrict__ dt_g,  const float* __restrict__ h0,
    const float* __restrict__ W_hh,  const float* __restrict__ dec_W,
    const int*   __restrict__ seq_types,
    const float* __restrict__ tabH,  const float* __restrict__ tabD,
    float* __restrict__ out)
{
    __shared__ __align__(16) _Float16 h16[2][HD];
    __shared__ float dts[SEQ];
    __shared__ int   tys[SEQ + 2];

    const int b    = blockIdx.x;
    const int tid  = threadIdx.x;
    const int lane = tid & 63;
    const int b0 = lane & 1, b1 = (lane >> 1) & 1;
    const int b2 = (lane >> 2) & 1, b3 = (lane >> 3) & 1;
    const int G    = (tid >> 6) * 4 + ((lane >> 4) & 3);  // row quad 0..31
    const int row  = 4 * G + 2 * b0 + b1;
    const int chunk = b0 | (b1 << 1) | (b3 << 2);         // h-col block /16
    const bool cls3 = (b2 & b3);                          // LDS-writer lane

    // Stage dt / seq_types columns for this batch element.
    for (int t = tid; t < SEQ; t += 512) {
        dts[t] = dt_g[(size_t)t * BAT + b];
        tys[t] = seq_types[(size_t)t * BAT + b];
    }
    if (tid < 2) tys[SEQ + tid] = 0;          // prefetch-pad
    if (tid < HD) h16[0][tid] = (_Float16)h0[b * HD + tid];

    // Load + convert this lane's weight block (4 rows x 16 cols) to f16x2.
    const size_t rstr = b2 ? (size_t)(KD + HD) : (size_t)HD;
    const float* wb = (b2 ? (dec_W + KD) : W_hh) + (size_t)(4 * G) * rstr
                      + chunk * 16;
#define LW8(D0,D1,D2,D3,D4,D5,D6,D7,P) { \
    const float4 _a = *reinterpret_cast<const float4*>(P);        \
    const float4 _b = *reinterpret_cast<const float4*>((P) + 4);  \
    const float4 _c = *reinterpret_cast<const float4*>((P) + 8);  \
    const float4 _d = *reinterpret_cast<const float4*>((P) + 12); \
    D0 = PK(_a.x,_a.y); D1 = PK(_a.z,_a.w); D2 = PK(_b.x,_b.y); D3 = PK(_b.z,_b.w); \
    D4 = PK(_c.x,_c.y); D5 = PK(_c.z,_c.w); D6 = PK(_d.x,_d.y); D7 = PK(_d.z,_d.w); }
    int w00,w01,w02,w03,w04,w05,w06,w07;
    int w10,w11,w12,w13,w14,w15,w16,w17;
    int w20,w21,w22,w23,w24,w25,w26,w27;
    int w30,w31,w32,w33,w34,w35,w36,w37;
    LW8(w00,w01,w02,w03,w04,w05,w06,w07, wb + 0 * rstr)
    LW8(w10,w11,w12,w13,w14,w15,w16,w17, wb + 1 * rstr)
    LW8(w20,w21,w22,w23,w24,w25,w26,w27, wb + 2 * rstr)
    LW8(w30,w31,w32,w33,w34,w35,w36,w37, wb + 3 * rstr)
#undef LW8
    PIN(w00);PIN(w01);PIN(w02);PIN(w03);PIN(w04);PIN(w05);PIN(w06);PIN(w07);
    PIN(w10);PIN(w11);PIN(w12);PIN(w13);PIN(w14);PIN(w15);PIN(w16);PIN(w17);
    PIN(w20);PIN(w21);PIN(w22);PIN(w23);PIN(w24);PIN(w25);PIN(w26);PIN(w27);
    PIN(w30);PIN(w31);PIN(w32);PIN(w33);PIN(w34);PIN(w35);PIN(w36);PIN(w37);

    const float* tabp = (b2 ? tabD : tabH) + row;

    // Per-lane 32-bit element offset for the single global store this lane
    // owns (advanced by BAT*HD per step). Class 3 never stores.
    unsigned off = (unsigned)(b2 ? (b3 ? 0u : (unsigned)SEQ * BAT * HD)
                                 : (b3 ? 2u * SEQ * BAT * HD : 0u))
                   + (unsigned)(b * HD + row);

    __syncthreads();   // staging visible

    // Table prefetch pipeline (2 steps ahead; tables are L2-resident).
    float tab_cur = tabp[tys[0] * HD];
    float tab_nxt = tabp[tys[1] * HD];

#define DOT8(A,W0,W1,W2,W3,W4,W5,W6,W7) \
    A = fdot2(W0, hv0.x, A); A = fdot2(W1, hv0.y, A); \
    A = fdot2(W2, hv0.z, A); A = fdot2(W3, hv0.w, A); \
    A = fdot2(W4, hv1.x, A); A = fdot2(W5, hv1.y, A); \
    A = fdot2(W6, hv1.z, A); A = fdot2(W7, hv1.w, A);

#define STEP(P, TT) { \
    const float tab_pf = tabp[tys[(TT) + 2] * HD];   /* use at TT+2 */ \
    const float dtv    = dts[TT]; \
    const int4 hv0 = *reinterpret_cast<const int4*>(&h16[P][chunk * 16]); \
    const int4 hv1 = *reinterpret_cast<const int4*>(&h16[P][chunk * 16 + 8]); \
    float a0 = 0.f, a1 = 0.f, a2 = 0.f, a3 = 0.f; \
    DOT8(a0, w00,w01,w02,w03,w04,w05,w06,w07) \
    DOT8(a1, w10,w11,w12,w13,w14,w15,w16,w17) \
    DOT8(a2, w20,w21,w22,w23,w24,w25,w26,w27) \
    DOT8(a3, w30,w31,w32,w33,w34,w35,w36,w37) \
    /* value-halving: xor1 resolves row-bit1, xor2 resolves row-bit0 */ \
    const float t0 = dpp_add<0xB1>(b0 ? a2 : a0, b0 ? a0 : a2); \
    const float t1 = dpp_add<0xB1>(b0 ? a3 : a1, b0 ? a1 : a3); \
    const float u  = dpp_add<0x4E>(b1 ? t1 : t0, b1 ? t0 : t1); \
    /* xor8 plain add completes the 8-chunk sum */ \
    const float sv = dpp_add<0x128>(u, u) + tab_cur; \
    /* activations (branchless; all lanes both paths) */ \
    const float e2 = __expf(2.f * sv); \
    const float vh = 1.f - __fdividef(2.f, e2 + 1.f);            /* tanh */ \
    const float z  = 10.f * sv; \
    const float em = __expf(-fabsf(z)); \
    const float sp = 0.1f * (fmaxf(z, 0.f) + __logf(1.f + em));  /* softplus10 */ \
    const float vd = __expf(-sp * dtv); \
    const float v  = b2 ? vd : vh; \
    /* type exchange lane^4: row_ror:4 / row_ror:12 + select */ \
    const float x4  = dpp_mov<0x124>(v); \
    const float x12 = dpp_mov<0x12C>(v); \
    const float cross = b2 ? x12 : x4; \
    const float hnew  = v * cross; \
    if (cls3) { \
        h16[(P) ^ 1][row] = (_Float16)hnew; \
    } else { \
        const float stv = b2 ? sp : (b3 ? hnew : v); \
        out[off] = stv; \
    } \
    off += BAT * HD; \
    tab_cur = tab_nxt; \
    tab_nxt = tab_pf; \
    STEP_BARRIER(); \
}

    for (int t = 0; t < SEQ; t += 2) {
        STEP(0, t)
        STEP(1, t + 1)
    }
#undef STEP
#undef DOT8
}

extern "C" void kernel_launch(void* const* d_in, const int* in_sizes, int n_in,
                              void* d_out, int out_size, void* d_ws, size_t ws_size,
                              hipStream_t stream) {
    const float* dt        = (const float*)d_in[0];
    const float* h0        = (const float*)d_in[1];
    const float* embed_W   = (const float*)d_in[2];
    const float* W_ih      = (const float*)d_in[3];
    const float* b_ih      = (const float*)d_in[4];
    const float* W_hh      = (const float*)d_in[5];
    const float* b_hh      = (const float*)d_in[6];
    const float* dec_W     = (const float*)d_in[7];
    const float* dec_b     = (const float*)d_in[8];
    const int*   seq_types = (const int*)  d_in[9];
    float* out  = (float*)d_out;

    float* tabHw = (float*)d_ws;                 // [65][128]
    float* tabDw = tabHw + (KD + 1) * HD;        // [65][128]

    precompute_tables<<<KD + 1, 128, 0, stream>>>(embed_W, W_ih, b_ih, b_hh,
                                                  dec_W, dec_b, tabHw, tabDw);
    hawkes_rnn<<<BAT, 512, 0, stream>>>(dt, h0, W_hh, dec_W, seq_types,
                                        tabHw, tabDw, out);
}